// Round 1
// baseline (202.327 us; speedup 1.0000x reference)
//
#include <hip/hip_runtime.h>

#define T_SZ 16384
#define CIN  8
#define COUT 8
#define SEG  4096
#define NSEG (T_SZ / SEG)

struct V3 { float x, y, z; };

__device__ __forceinline__ V3 mkv3(float a, float b, float c) { V3 r; r.x = a; r.y = b; r.z = c; return r; }
__device__ __forceinline__ V3 vadd3(const V3& a, const V3& b) { return mkv3(a.x + b.x, a.y + b.y, a.z + b.z); }
__device__ __forceinline__ V3 vfma3(const V3& acc, float s, const V3& w) {
  return mkv3(fmaf(s, w.x, acc.x), fmaf(s, w.y, acc.y), fmaf(s, w.z, acc.z));
}
// A has rows (a0,a1,a2),(0,a1,a2),(0,0,a2): a_ss[s,n]=a[n] iff n>=s
__device__ __forceinline__ V3 aapp(float a0, float a1, float a2, const V3& v) {
  float t2 = a2 * v.z;
  float t1 = fmaf(a1, v.y, t2);
  return mkv3(fmaf(a0, v.x, t1), t1, t2);
}

__global__ __launch_bounds__(256) void ldtf_scan_kernel(
    const float* __restrict__ u, const float* __restrict__ x0,
    const float* __restrict__ ac, const float* __restrict__ bc,
    float* __restrict__ out)
{
  __shared__ float s_bu[SEG];      // FIR output tile (uniform part of elements)
  __shared__ V3 s_rho[SEG / 2];    // states at odd local t (only these are re-read)
  __shared__ V3 s_part[4];         // cross-wave reduce scratch
  __shared__ V3 s_g[13];           // g[k] = A^k * ones
  __shared__ V3 s_h[13];           // h[q] = A^q e0 + A^(q-1) e1  (h[0] = e0)
  __shared__ V3 s_carry;           // rho at previous segment end
  __shared__ V3 s_eps;             // this segment's full reduction

  const int tid = threadIdx.x;
  const int bid = blockIdx.x;
  // XCD swizzle: the 8 o-blocks of one b land on the same XCD (bid % 8 const)
  const int o = (bid >> 3) & 7;
  const int b = (bid & 7) + ((bid >> 6) << 3);

  const float a0 = ac[0 * COUT + o];
  const float a1 = ac[1 * COUT + o];
  const float a2 = ac[2 * COUT + o];

  float wbc[4][8];
#pragma unroll
  for (int w = 0; w < 4; ++w)
#pragma unroll
    for (int i = 0; i < CIN; ++i)
      wbc[w][i] = bc[(w * CIN + i) * COUT + o];

  const float* ub = u + (size_t)b * T_SZ * CIN;
  float* ob = out + (size_t)b * T_SZ * COUT + o;

  V3 Psave = mkv3(0, 0, 0), eps2save = mkv3(0, 0, 0); // used by tid 0 only

  for (int s = 0; s < NSEG; ++s) {
    // ---- FIR: b_u[t] = sum_{w,i} u[t-3+w, i] * bc[w,i,o], zero-padded front ----
#pragma unroll
    for (int j = 0; j < SEG / 256; ++j) {
      int tl = j * 256 + tid;
      int t = s * SEG + tl;
      float acc = 0.f;
#pragma unroll
      for (int w = 0; w < 4; ++w) {
        int tt = t - 3 + w;
        if (tt >= 0) {
          const float* ur = ub + (size_t)tt * CIN;
#pragma unroll
          for (int i = 0; i < CIN; ++i) acc = fmaf(ur[i], wbc[w][i], acc);
        }
      }
      s_bu[tl] = acc;
    }
    __syncthreads();

    if (s == 0) {
      if (tid == 0) {
        V3 g = mkv3(1.f, 1.f, 1.f);
        s_g[0] = g;
        for (int k = 1; k <= 12; ++k) { g = aapp(a0, a1, a2, g); s_g[k] = g; }
        float x00 = x0[((size_t)b * 3 + 0) * COUT + o];
        float x01 = x0[((size_t)b * 3 + 1) * COUT + o];
        float x02 = x0[((size_t)b * 3 + 2) * COUT + o];
        // first = b_u[0] + a2*x0[0] + a1*x0[1] + a0*x0[2]  (flip(a) einsum)
        float first = s_bu[0] + a2 * x00 + a1 * x01 + a0 * x02;
        V3 e0 = mkv3(first, x02, x01);          // stacked[:, :, 0]
        V3 e1 = mkv3(s_bu[1], s_bu[1], x02);    // stacked[:, :, 1]
        s_h[0] = e0;
        V3 h = vadd3(aapp(a0, a1, a2, e0), e1); // h1 = A e0 + e1
        s_h[1] = h;
        for (int k = 2; k <= 12; ++k) { h = aapp(a0, a1, a2, h); s_h[k] = h; }
      }
      __syncthreads();
    }

    // ---- eps_s: whole-segment reduction, weights g[12 - popc(r)] ----
    {
      V3 p = mkv3(0, 0, 0);
      int base = tid * 16;
#pragma unroll
      for (int rr = 0; rr < 16; ++rr) {
        int idx = base + rr;
        if (s == 0 && idx < 2) continue;   // e0,e1 folded via h[12]
        p = vfma3(p, s_bu[idx], s_g[12 - __popc(idx)]);
      }
#pragma unroll
      for (int off = 32; off >= 1; off >>= 1) {
        p.x += __shfl_down(p.x, off, 64);
        p.y += __shfl_down(p.y, off, 64);
        p.z += __shfl_down(p.z, off, 64);
      }
      if ((tid & 63) == 0) s_part[tid >> 6] = p;
      __syncthreads();
      if (tid == 0) {
        V3 e = vadd3(vadd3(s_part[0], s_part[1]), vadd3(s_part[2], s_part[3]));
        if (s == 0) e = vadd3(e, s_h[12]);
        s_eps = e;
      }
      __syncthreads();
    }

    const int tg0 = s * SEG;
    // ---- interior down-sweep: phases q = 11 .. 0 over local t with ctz(tl+1)==q ----
    for (int q = 11; q >= 0; --q) {
      if (q <= 3) {
        int nout = SEG >> (q + 1);
        for (int j = tid; j < nout; j += 256) {
          int tl = ((2 * j + 1) << q) - 1;
          int base = j << (q + 1);
          V3 E = mkv3(0, 0, 0);
          for (int rr = 0; rr < (1 << q); ++rr) {
            if (s == 0 && j == 0 && rr < 2) continue;
            E = vfma3(E, s_bu[base + rr], s_g[q - __popc(rr)]);
          }
          V3 val;
          if (j == 0) {
            if (s == 0) val = vadd3(s_h[q], E);
            else        val = vadd3(aapp(a0, a1, a2, s_carry), E);
          } else {
            val = vadd3(aapp(a0, a1, a2, s_rho[(tl - (1 << q)) >> 1]), E);
          }
          ob[(size_t)(tg0 + tl) * COUT] = val.x;
          if (q >= 1) s_rho[tl >> 1] = val;
        }
        __syncthreads();
      } else {
        int lg = q - 3;                 // group size 2^(q-3), every thread sums 8 elems
        int gsz = 1 << lg;
        int j = tid >> lg;
        int k = tid & (gsz - 1);
        int tl = ((2 * j + 1) << q) - 1;
        int bbase = (j << (q + 1)) + (k << 3);
        V3 E = mkv3(0, 0, 0);
#pragma unroll
        for (int rr = 0; rr < 8; ++rr) {
          int rblk = (k << 3) + rr;
          if (s == 0 && j == 0 && rblk < 2) continue;
          E = vfma3(E, s_bu[bbase + rr], s_g[q - __popc(rblk)]);
        }
        int red = (gsz < 64) ? gsz : 64;
        for (int off = red >> 1; off >= 1; off >>= 1) {
          E.x += __shfl_down(E.x, off, red);
          E.y += __shfl_down(E.y, off, red);
          E.z += __shfl_down(E.z, off, red);
        }
        if (gsz > 64) {                  // q=10 (2 waves/group), q=11 (4 waves/group)
          if ((tid & 63) == 0) s_part[tid >> 6] = E;
          __syncthreads();
          if (k == 0) {
            int wv0 = tid >> 6, nw = gsz >> 6;
            V3 Es = s_part[wv0];
            for (int w2 = 1; w2 < nw; ++w2) Es = vadd3(Es, s_part[wv0 + w2]);
            E = Es;
          }
        }
        if (k == 0) {
          V3 val;
          if (j == 0) {
            if (s == 0) val = vadd3(s_h[q], E);
            else        val = vadd3(aapp(a0, a1, a2, s_carry), E);
          } else {
            val = vadd3(aapp(a0, a1, a2, s_rho[(tl - (1 << q)) >> 1]), E);
          }
          ob[(size_t)(tg0 + tl) * COUT] = val.x;
          s_rho[tl >> 1] = val;
        }
        __syncthreads();
      }
    }

    // ---- segment boundary output (local t = 4095) + carry, per 4-elem top tree ----
    if (tid == 0) {
      V3 eps = s_eps;
      V3 bnd;
      if (s == 0) {
        bnd = eps;                                        // rho(4095)  = eps0
      } else if (s == 1) {
        bnd = vadd3(aapp(a0, a1, a2, s_carry), eps);      // rho(8191)  = A eps0 + eps1
        Psave = bnd;
      } else if (s == 2) {
        bnd = vadd3(aapp(a0, a1, a2, s_carry), eps);      // rho(12287) = A P + eps2
        eps2save = eps;
      } else {
        V3 t1 = aapp(a0, a1, a2, Psave);                  // rho(16383) = A P + (A eps2 + eps3)
        V3 t2 = aapp(a0, a1, a2, eps2save);
        bnd = vadd3(vadd3(t1, t2), eps);
      }
      ob[(size_t)(tg0 + SEG - 1) * COUT] = bnd.x;
      s_carry = bnd;
    }
    __syncthreads();
  }
}

extern "C" void kernel_launch(void* const* d_in, const int* in_sizes, int n_in,
                              void* d_out, int out_size, void* d_ws, size_t ws_size,
                              hipStream_t stream) {
  const float* u  = (const float*)d_in[0];
  const float* x0 = (const float*)d_in[1];
  const float* ac = (const float*)d_in[2];
  const float* bc = (const float*)d_in[3];
  float* out = (float*)d_out;
  (void)d_ws; (void)ws_size; (void)in_sizes; (void)n_in; (void)out_size;
  ldtf_scan_kernel<<<dim3(512), dim3(256), 0, stream>>>(u, x0, ac, bc, out);
}

// Round 2
// 181.518 us; speedup vs baseline: 1.1146x; 1.1146x over previous
//
#include <hip/hip_runtime.h>

#define T_SZ 16384
#define CIN  8
#define COUT 8
#define NTHR 1024

struct V3 { float x, y, z; };
__device__ __forceinline__ V3 mkv3(float a, float b, float c) { V3 r; r.x=a; r.y=b; r.z=c; return r; }
__device__ __forceinline__ V3 vadd3(V3 a, V3 b) { return mkv3(a.x+b.x, a.y+b.y, a.z+b.z); }
__device__ __forceinline__ V3 vfma3(V3 acc, float s, V3 w) {
  return mkv3(fmaf(s, w.x, acc.x), fmaf(s, w.y, acc.y), fmaf(s, w.z, acc.z));
}
// A rows: (a0,a1,a2),(0,a1,a2),(0,0,a2)
__device__ __forceinline__ V3 aappf(float a0, float a1, float a2, V3 v) {
  float t2 = a2 * v.z;
  float t1 = fmaf(a1, v.y, t2);
  return mkv3(fmaf(a0, v.x, t1), t1, t2);
}

struct Row { float4 lo, hi; };
__device__ __forceinline__ Row ldrow(const float* p) {
  Row r; r.lo = *(const float4*)p; r.hi = *(const float4*)(p + 4); return r;
}
__device__ __forceinline__ Row zrow() { Row r; r.lo = make_float4(0.f,0.f,0.f,0.f); r.hi = r.lo; return r; }
__device__ __forceinline__ float rdot(const Row& r, const float* w) {
  float s = r.lo.x * w[0];
  s = fmaf(r.lo.y, w[1], s); s = fmaf(r.lo.z, w[2], s); s = fmaf(r.lo.w, w[3], s);
  s = fmaf(r.hi.x, w[4], s); s = fmaf(r.hi.y, w[5], s); s = fmaf(r.hi.z, w[6], s);
  s = fmaf(r.hi.w, w[7], s);
  return s;
}

// Tree level beta (block of 2^beta 16-step leaves) lives at s_tr[1024 - (2048>>beta) ...]
__global__ __launch_bounds__(NTHR, 4) void ldtf_kernel(
    const float* __restrict__ u, const float* __restrict__ x0,
    const float* __restrict__ ac, const float* __restrict__ bc,
    float* __restrict__ out)
{
  __shared__ V3 s_E4[1024];   // 12 KB: leaf states per 16-block
  __shared__ V3 s_tr[1023];   // 12 KB: upper tree levels beta=1..9 + (root computed inline)

  const int j = threadIdx.x;
  const int bid = blockIdx.x;
  const int b = bid & 63;     // same-b WGs share XCD (bid%8 == b%8) for u L2 reuse
  const int o = bid >> 6;

  const float a0 = ac[0*COUT + o];
  const float a1 = ac[1*COUT + o];
  const float a2 = ac[2*COUT + o];

  float w0[8], w1[8], w2[8], w3[8];
#pragma unroll
  for (int i = 0; i < 8; ++i) {
    w0[i] = bc[(0*CIN + i)*COUT + o];
    w1[i] = bc[(1*CIN + i)*COUT + o];
    w2[i] = bc[(2*CIN + i)*COUT + o];
    w3[i] = bc[(3*CIN + i)*COUT + o];
  }

  const float* ub = u + (size_t)b * T_SZ * CIN;
  float* ob = out + (size_t)b * T_SZ * COUT + o;
  const int t0 = j * 16;

  // ---- FIR into registers: bv[r] = sum_w dot(u[t0+r-3+w], w_w), zero-padded front ----
  float bv[16];
  {
    Row ra, rb, rc;
    if (j == 0) { ra = zrow(); rb = zrow(); rc = zrow(); }
    else {
      ra = ldrow(ub + (size_t)(t0 - 3) * CIN);
      rb = ldrow(ub + (size_t)(t0 - 2) * CIN);
      rc = ldrow(ub + (size_t)(t0 - 1) * CIN);
    }
#pragma unroll
    for (int r = 0; r < 16; ++r) {
      Row rd = ldrow(ub + (size_t)(t0 + r) * CIN);
      float s = rdot(ra, w0) + rdot(rb, w1) + rdot(rc, w2) + rdot(rd, w3);
      bv[r] = s;
      ra = rb; rb = rc; rc = rd;
    }
  }

  // ---- specials (thread 0 only): e0=(first,x0_2,x0_1), e1=(b1,b1,x0_2) ----
  V3 e0 = mkv3(0,0,0), e1 = mkv3(0,0,0);
  if (j == 0) {
    float x00 = x0[((size_t)b*3 + 0)*COUT + o];
    float x01 = x0[((size_t)b*3 + 1)*COUT + o];
    float x02 = x0[((size_t)b*3 + 2)*COUT + o];
    float first = bv[0] + a2*x00 + a1*x01 + a0*x02;
    e0 = mkv3(first, x02, x01);
    e1 = mkv3(bv[1], bv[1], x02);
  }

  // ---- leaf E4 = sum_r A^(4-popc(r)) * e[r] ----
  V3 gt[5];
  gt[0] = mkv3(1.f,1.f,1.f);
  gt[1] = aappf(a0,a1,a2, gt[0]);
  gt[2] = aappf(a0,a1,a2, gt[1]);
  gt[3] = aappf(a0,a1,a2, gt[2]);
  gt[4] = aappf(a0,a1,a2, gt[3]);
  {
    V3 acc;
    if (j == 0) {
      V3 p0 = aappf(a0,a1,a2, aappf(a0,a1,a2, aappf(a0,a1,a2, aappf(a0,a1,a2, e0))));
      V3 p1 = aappf(a0,a1,a2, aappf(a0,a1,a2, aappf(a0,a1,a2, e1)));
      acc = vadd3(p0, p1);
#pragma unroll
      for (int r = 2; r < 16; ++r) acc = vfma3(acc, bv[r], gt[4 - __popc(r)]);
    } else {
      acc = mkv3(0,0,0);
#pragma unroll
      for (int r = 0; r < 16; ++r) acc = vfma3(acc, bv[r], gt[4 - __popc(r)]);
    }
    s_E4[j] = acc;
  }
  __syncthreads();

  // ---- up-sweep: E_{q+1} = A*E_left + E_right ----
  if (j < 512) s_tr[j]        = vadd3(aappf(a0,a1,a2, s_E4[2*j]),       s_E4[2*j+1]);
  __syncthreads();
  if (j < 256) s_tr[512 + j]  = vadd3(aappf(a0,a1,a2, s_tr[2*j]),       s_tr[2*j+1]);
  __syncthreads();
  if (j < 128) s_tr[768 + j]  = vadd3(aappf(a0,a1,a2, s_tr[512 + 2*j]), s_tr[512 + 2*j+1]);
  __syncthreads();
  if (j < 64)  s_tr[896 + j]  = vadd3(aappf(a0,a1,a2, s_tr[768 + 2*j]), s_tr[768 + 2*j+1]);
  __syncthreads();
  if (j < 32)  s_tr[960 + j]  = vadd3(aappf(a0,a1,a2, s_tr[896 + 2*j]), s_tr[896 + 2*j+1]);
  __syncthreads();
  if (j < 16)  s_tr[992 + j]  = vadd3(aappf(a0,a1,a2, s_tr[960 + 2*j]), s_tr[960 + 2*j+1]);
  __syncthreads();
  if (j < 8)   s_tr[1008 + j] = vadd3(aappf(a0,a1,a2, s_tr[992 + 2*j]), s_tr[992 + 2*j+1]);
  __syncthreads();
  if (j < 4)   s_tr[1016 + j] = vadd3(aappf(a0,a1,a2, s_tr[1008 + 2*j]), s_tr[1008 + 2*j+1]);
  __syncthreads();
  if (j < 2)   s_tr[1020 + j] = vadd3(aappf(a0,a1,a2, s_tr[1016 + 2*j]), s_tr[1016 + 2*j+1]);
  __syncthreads();
  if (j == 0) {  // root = E_14(whole) = rho(16383)
    V3 root = vadd3(aappf(a0,a1,a2, s_tr[1020]), s_tr[1021]);
    ob[(size_t)(T_SZ - 1) * COUT] = root.x;
  }

  // ---- sigma(j) = rho(16j - 1): fold Fenwick chain of j, high bit -> low bit ----
  V3 sig = mkv3(0,0,0);
#pragma unroll
  for (int be = 9; be >= 1; --be) {
    if ((j >> be) & 1) {
      const int off = 1024 - (2048 >> be);
      sig = vadd3(aappf(a0,a1,a2, sig), s_tr[off + (j >> be) - 1]);
    }
  }
  if (j & 1) sig = vadd3(aappf(a0,a1,a2, sig), s_E4[j - 1]);
  if (j > 0) ob[(size_t)(t0 - 1) * COUT] = sig.x;

  // ---- local binary-counter scan: outputs t0 .. t0+14 ----
  {
    V3 st[5];
#pragma unroll
    for (int r = 0; r < 16; ++r) {
      V3 v = mkv3(bv[r], bv[r], bv[r]);
      if (j == 0) { if (r == 0) v = e0; if (r == 1) v = e1; }
      if (r & 1)          v = vadd3(aappf(a0,a1,a2, st[0]), v);
      if ((r & 3) == 3)   v = vadd3(aappf(a0,a1,a2, st[1]), v);
      if ((r & 7) == 7)   v = vadd3(aappf(a0,a1,a2, st[2]), v);
      if ((r & 15) == 15) v = vadd3(aappf(a0,a1,a2, st[3]), v);
      const int lvl = (r & 1) ? (((r & 3) == 3) ? (((r & 7) == 7) ? (((r & 15) == 15) ? 4 : 3) : 2) : 1) : 0;
      st[lvl] = v;
      if (r < 15) {
        const int i = r + 1;
        V3 acc = sig;
        if (i & 8) acc = vadd3(aappf(a0,a1,a2, acc), st[3]);
        if (i & 4) acc = vadd3(aappf(a0,a1,a2, acc), st[2]);
        if (i & 2) acc = vadd3(aappf(a0,a1,a2, acc), st[1]);
        if (i & 1) acc = vadd3(aappf(a0,a1,a2, acc), st[0]);
        ob[(size_t)(t0 + r) * COUT] = acc.x;
      }
    }
  }
}

extern "C" void kernel_launch(void* const* d_in, const int* in_sizes, int n_in,
                              void* d_out, int out_size, void* d_ws, size_t ws_size,
                              hipStream_t stream) {
  const float* u  = (const float*)d_in[0];
  const float* x0 = (const float*)d_in[1];
  const float* ac = (const float*)d_in[2];
  const float* bc = (const float*)d_in[3];
  float* out = (float*)d_out;
  (void)d_ws; (void)ws_size; (void)in_sizes; (void)n_in; (void)out_size;
  ldtf_kernel<<<dim3(512), dim3(NTHR), 0, stream>>>(u, x0, ac, bc, out);
}